// Round 1
// baseline (308.794 us; speedup 1.0000x reference)
//
#include <hip/hip_runtime.h>
#include <stdint.h>

#define NDIM 512
#define HEADS 8
#define DHEAD 64
#define NSEQ 4096
#define BATCH 8
#define ROWS (BATCH * NSEQ)   // 32768
#define QKVN (3 * NDIM)       // 1536

typedef unsigned short ushort_t;
typedef __bf16 bf16x8 __attribute__((ext_vector_type(8)));
typedef float f32x4 __attribute__((ext_vector_type(4)));
typedef unsigned short u16x8 __attribute__((ext_vector_type(8)));

__device__ __forceinline__ ushort_t f2bf(float f) {
  union { float f; uint32_t u; } v; v.f = f;
  uint32_t r = (v.u + 0x7FFFu + ((v.u >> 16) & 1u)) >> 16;
  return (ushort_t)r;
}
__device__ __forceinline__ float bf2f(ushort_t h) {
  union { uint32_t u; float f; } v; v.u = ((uint32_t)h) << 16;
  return v.f;
}

__device__ __forceinline__ void gload_lds16(const void* g, void* l) {
  __builtin_amdgcn_global_load_lds(
      (__attribute__((address_space(1))) void*)(g),
      (__attribute__((address_space(3))) void*)(l), 16, 0, 0);
}

// ---------- prep: transpose+cast weights to bf16 B^T layout ----------
__global__ __launch_bounds__(256) void prep_k(const float* __restrict__ w_qkv,
                                              const float* __restrict__ w_out,
                                              ushort_t* __restrict__ wqkvT,
                                              ushort_t* __restrict__ woutT) {
  int id = blockIdx.x * 256 + threadIdx.x;
  if (id < QKVN * NDIM) {
    int n = id >> 9, k = id & 511;
    wqkvT[id] = f2bf(w_qkv[k * QKVN + n]);
  } else {
    int id2 = id - QKVN * NDIM;
    if (id2 < NDIM * NDIM) {
      int n = id2 >> 9, k = id2 & 511;
      woutT[id2] = f2bf(w_out[k * NDIM + n]);
    }
  }
}

// ---------- rmsnorm: xn = x/||x|| * sqrt(512) * gamma, bf16 out ----------
__global__ __launch_bounds__(256) void rmsnorm_k(const float* __restrict__ x,
                                                 const float* __restrict__ gamma,
                                                 ushort_t* __restrict__ xn) {
  int wave = threadIdx.x >> 6, lane = threadIdx.x & 63;
  size_t row = (size_t)blockIdx.x * 4 + wave;
  const float4* xr = (const float4*)(x + row * NDIM);
  float4 v0 = xr[lane * 2], v1 = xr[lane * 2 + 1];
  float s = v0.x*v0.x + v0.y*v0.y + v0.z*v0.z + v0.w*v0.w
          + v1.x*v1.x + v1.y*v1.y + v1.z*v1.z + v1.w*v1.w;
#pragma unroll
  for (int off = 32; off; off >>= 1) s += __shfl_xor(s, off, 64);
  float scale = 22.627416997969522f / fmaxf(sqrtf(s), 1e-12f);
  const float4* gr = (const float4*)gamma;
  float4 g0 = gr[lane * 2], g1 = gr[lane * 2 + 1];
  u16x8 o;
  o[0] = f2bf(v0.x * scale * g0.x);
  o[1] = f2bf(v0.y * scale * g0.y);
  o[2] = f2bf(v0.z * scale * g0.z);
  o[3] = f2bf(v0.w * scale * g0.w);
  o[4] = f2bf(v1.x * scale * g1.x);
  o[5] = f2bf(v1.y * scale * g1.y);
  o[6] = f2bf(v1.z * scale * g1.z);
  o[7] = f2bf(v1.w * scale * g1.w);
  *(u16x8*)(xn + row * NDIM + lane * 8) = o;
}

// ---------- m97-style 128x128 bf16 GEMM, C = A[M,K] @ BT[N,K]^T ----------
__device__ __forceinline__ void store_elem(float* C, size_t i, float v) { C[i] = v; }
__device__ __forceinline__ void store_elem(ushort_t* C, size_t i, float v) { C[i] = f2bf(v); }

template <typename T>
__global__ __launch_bounds__(256) void gemm_bt(const ushort_t* __restrict__ A,
                                               const ushort_t* __restrict__ BT,
                                               T* __restrict__ C,
                                               int M, int N, int K) {
  __shared__ ushort_t As[128 * 64];
  __shared__ ushort_t Bs[128 * 64];
  const int tid = threadIdx.x;
  const int lane = tid & 63;
  const int wave = tid >> 6;
  const int m0 = blockIdx.y * 128;
  const int n0 = blockIdx.x * 128;
  const int wm = (wave >> 1) * 64;
  const int wn = (wave & 1) * 64;
  const int srow = lane >> 3;
  const int scol = (lane & 7) * 16;  // bytes
  const int r = lane & 15, q = lane >> 4;

  f32x4 acc[4][4] = {};

  for (int k0 = 0; k0 < K; k0 += 64) {
    __syncthreads();
#pragma unroll
    for (int c = 0; c < 4; ++c) {
      int chunk = wave * 4 + c;
      int row = chunk * 8 + srow;
      gload_lds16((const char*)(A + (size_t)(m0 + row) * K + k0) + scol,
                  (char*)As + chunk * 1024);
      gload_lds16((const char*)(BT + (size_t)(n0 + row) * K + k0) + scol,
                  (char*)Bs + chunk * 1024);
    }
    __syncthreads();
#pragma unroll
    for (int kk = 0; kk < 64; kk += 32) {
      bf16x8 af[4], bfr[4];
#pragma unroll
      for (int i = 0; i < 4; ++i)
        af[i] = *(const bf16x8*)(const void*)(As + (wm + i * 16 + r) * 64 + kk + q * 8);
#pragma unroll
      for (int j = 0; j < 4; ++j)
        bfr[j] = *(const bf16x8*)(const void*)(Bs + (wn + j * 16 + r) * 64 + kk + q * 8);
#pragma unroll
      for (int i = 0; i < 4; ++i)
#pragma unroll
        for (int j = 0; j < 4; ++j)
          acc[i][j] = __builtin_amdgcn_mfma_f32_16x16x32_bf16(af[i], bfr[j], acc[i][j], 0, 0, 0);
    }
  }
#pragma unroll
  for (int i = 0; i < 4; ++i)
#pragma unroll
    for (int j = 0; j < 4; ++j) {
      int col = n0 + wn + j * 16 + r;
#pragma unroll
      for (int v = 0; v < 4; ++v) {
        int rw = m0 + wm + i * 16 + q * 4 + v;
        store_elem(C, (size_t)rw * N + col, acc[i][j][v]);
      }
    }
}

// ---------- gram partial: G[d,e] += sum_n Q[n,d]K[n,e], + col sumsq ----------
// grid (8 chunks, 64 bh). LDS tiles transposed [d][n] with XOR-swizzled cols.
__global__ __launch_bounds__(256) void gram_k(const ushort_t* __restrict__ qkv,
                                              float* __restrict__ pG,
                                              float* __restrict__ pSq) {
  int chunk = blockIdx.x;  // 0..7  (n range chunk*512..+512)
  int bh = blockIdx.y;     // 0..63
  int b = bh >> 3, h = bh & 7;
  __shared__ ushort_t Qt[64 * 72];
  __shared__ ushort_t Kt[64 * 72];
  __shared__ float sq[128];
  int tid = threadIdx.x, lane = tid & 63, wave = tid >> 6;
  int nl = tid >> 2;          // 0..63 local n
  int dp = (tid & 3) * 16;    // d part
  int r = lane & 15, q = lane >> 4;
  float aq[16] = {}, ak[16] = {};
  f32x4 acc[4] = {};
  size_t base_row = ((size_t)b * NSEQ + (size_t)chunk * 512) * QKVN + (size_t)h * DHEAD;
  int swz_n = ((nl >> 3) & 7);

  for (int sc = 0; sc < 8; ++sc) {
    __syncthreads();
    size_t g = base_row + (size_t)(sc * 64 + nl) * QKVN;
    u16x8 qv0 = *(const u16x8*)(qkv + g + dp);
    u16x8 qv1 = *(const u16x8*)(qkv + g + dp + 8);
    u16x8 kv0 = *(const u16x8*)(qkv + g + NDIM + dp);
    u16x8 kv1 = *(const u16x8*)(qkv + g + NDIM + dp + 8);
#pragma unroll
    for (int i = 0; i < 8; ++i) {
      int d0 = dp + i, d1 = dp + 8 + i;
      int c0 = (nl & 7) | (((swz_n ^ (d0 >> 3)) & 7) << 3);
      int c1 = (nl & 7) | (((swz_n ^ (d1 >> 3)) & 7) << 3);
      float fq = bf2f(qv0[i]); aq[i] += fq * fq;      Qt[d0 * 72 + c0] = qv0[i];
      float fq2 = bf2f(qv1[i]); aq[8 + i] += fq2 * fq2; Qt[d1 * 72 + c1] = qv1[i];
      float fk = bf2f(kv0[i]); ak[i] += fk * fk;      Kt[d0 * 72 + c0] = kv0[i];
      float fk2 = bf2f(kv1[i]); ak[8 + i] += fk2 * fk2; Kt[d1 * 72 + c1] = kv1[i];
    }
    __syncthreads();
#pragma unroll
    for (int ks = 0; ks < 64; ks += 32) {
      int kb = (ks >> 3) + q;  // k block 0..7
      int m = wave * 16 + r;
      bf16x8 a = *(const bf16x8*)(const void*)(Qt + m * 72 + (((kb ^ (m >> 3)) & 7) << 3));
#pragma unroll
      for (int j = 0; j < 4; ++j) {
        int e = j * 16 + r;
        bf16x8 bb = *(const bf16x8*)(const void*)(Kt + e * 72 + (((kb ^ (e >> 3)) & 7) << 3));
        acc[j] = __builtin_amdgcn_mfma_f32_16x16x32_bf16(a, bb, acc[j], 0, 0, 0);
      }
    }
  }
  size_t gbase = ((size_t)bh * 8 + chunk) * 4096;
#pragma unroll
  for (int j = 0; j < 4; ++j)
#pragma unroll
    for (int v = 0; v < 4; ++v)
      pG[gbase + (size_t)(wave * 16 + q * 4 + v) * 64 + j * 16 + r] = acc[j][v];
  if (tid < 128) sq[tid] = 0.f;
  __syncthreads();
#pragma unroll
  for (int i = 0; i < 16; ++i) {
    atomicAdd(&sq[dp + i], aq[i]);
    atomicAdd(&sq[64 + dp + i], ak[i]);
  }
  __syncthreads();
  if (tid < 128) pSq[((size_t)bh * 8 + chunk) * 128 + tid] = sq[tid];
}

// ---------- finalize: norms + scale + softmax -> attn bf16 [bh][d][e] ----------
__global__ __launch_bounds__(64) void softmax_k(const float* __restrict__ pG,
                                                const float* __restrict__ pSq,
                                                const float* __restrict__ temp,
                                                ushort_t* __restrict__ attn) {
  int bh = blockIdx.x;
  int h = bh & 7;
  int d = threadIdx.x;
  __shared__ float kn[64];
  float sq = 0.f, sk = 0.f;
  for (int c = 0; c < 8; ++c) {
    sq += pSq[((size_t)bh * 8 + c) * 128 + d];
    sk += pSq[((size_t)bh * 8 + c) * 128 + 64 + d];
  }
  float qn = fmaxf(sqrtf(sq), 1e-12f);
  kn[d] = fmaxf(sqrtf(sk), 1e-12f);
  __syncthreads();
  float scale = 8.0f * expf(temp[h]) / qn;
  float row[64];
  for (int e = 0; e < 64; ++e) {
    float g = 0.f;
    for (int c = 0; c < 8; ++c) g += pG[((size_t)bh * 8 + c) * 4096 + d * 64 + e];
    row[e] = g * scale / kn[e];
  }
  float mx = -1e30f;
  for (int e = 0; e < 64; ++e) mx = fmaxf(mx, row[e]);
  float s = 0.f;
  for (int e = 0; e < 64; ++e) { row[e] = expf(row[e] - mx); s += row[e]; }
  float inv = 1.0f / s;
  for (int e = 0; e < 64; ++e) attn[(size_t)bh * 4096 + d * 64 + e] = f2bf(row[e] * inv);
}

// ---------- OT[n, h*64+d] = sum_e V[n,e]*attn[d,e] ----------
__global__ __launch_bounds__(256) void ot_k(const ushort_t* __restrict__ qkv,
                                            const ushort_t* __restrict__ attn,
                                            ushort_t* __restrict__ OT) {
  int nchunk = blockIdx.x;  // 0..31 (128 rows each)
  int bh = blockIdx.y;
  int b = bh >> 3, h = bh & 7;
  __shared__ ushort_t Vs[128 * 72];
  __shared__ ushort_t Am[64 * 72];
  int tid = threadIdx.x, lane = tid & 63, wave = tid >> 6;
  int r = lane & 15, q = lane >> 4;
  {  // stage attn [64][64] -> padded rows of 72
    int d = tid >> 2, p = (tid & 3) * 16;
    const u16x8* src = (const u16x8*)(attn + (size_t)bh * 4096 + d * 64 + p);
    *(u16x8*)(Am + d * 72 + p) = src[0];
    *(u16x8*)(Am + d * 72 + p + 8) = src[1];
  }
  {  // stage V [128][64] -> padded rows of 72 (half row / thread)
    int row = tid >> 1, p = (tid & 1) * 32;
    size_t vg = ((size_t)b * NSEQ + (size_t)nchunk * 128 + row) * QKVN + 2 * NDIM +
                (size_t)h * DHEAD + p;
    const u16x8* src = (const u16x8*)(qkv + vg);
    ushort_t* dst = Vs + row * 72 + p;
    *(u16x8*)(dst) = src[0];
    *(u16x8*)(dst + 8) = src[1];
    *(u16x8*)(dst + 16) = src[2];
    *(u16x8*)(dst + 24) = src[3];
  }
  __syncthreads();
  f32x4 acc[2][4] = {};
#pragma unroll
  for (int ks = 0; ks < 64; ks += 32) {
    bf16x8 av[2], bv[4];
#pragma unroll
    for (int i = 0; i < 2; ++i)
      av[i] = *(const bf16x8*)(const void*)(Vs + (wave * 32 + i * 16 + r) * 72 + ks + q * 8);
#pragma unroll
    for (int j = 0; j < 4; ++j)
      bv[j] = *(const bf16x8*)(const void*)(Am + (j * 16 + r) * 72 + ks + q * 8);
#pragma unroll
    for (int i = 0; i < 2; ++i)
#pragma unroll
      for (int j = 0; j < 4; ++j)
        acc[i][j] = __builtin_amdgcn_mfma_f32_16x16x32_bf16(av[i], bv[j], acc[i][j], 0, 0, 0);
  }
  size_t obase = ((size_t)b * NSEQ + (size_t)nchunk * 128) * NDIM + (size_t)h * DHEAD;
#pragma unroll
  for (int i = 0; i < 2; ++i)
#pragma unroll
    for (int j = 0; j < 4; ++j)
#pragma unroll
      for (int v = 0; v < 4; ++v)
        OT[obase + (size_t)(wave * 32 + i * 16 + q * 4 + v) * NDIM + j * 16 + r] =
            f2bf(acc[i][j][v]);
}

extern "C" void kernel_launch(void* const* d_in, const int* in_sizes, int n_in,
                              void* d_out, int out_size, void* d_ws, size_t ws_size,
                              hipStream_t stream) {
  (void)in_sizes; (void)n_in; (void)out_size; (void)ws_size;
  const float* x     = (const float*)d_in[0];
  const float* gamma = (const float*)d_in[1];
  const float* w_qkv = (const float*)d_in[2];
  const float* temp  = (const float*)d_in[3];
  const float* w_out = (const float*)d_in[4];
  float* out = (float*)d_out;
  char* ws = (char*)d_ws;

  // workspace layout (~130.5 MB):
  // [0, 96MB)        qkv bf16 [32768][1536]
  // [96MB, 128MB)    xn bf16 [32768][512]  -- after gemm1: pG (8MB) + pSq; then OT
  // [128MB, ...)     wqkvT (1.5MB), woutT (0.5MB), attn (0.5MB)
  ushort_t* qkv   = (ushort_t*)ws;
  ushort_t* xn    = (ushort_t*)(ws + (size_t)100663296);
  ushort_t* OT    = xn;
  float*    pG    = (float*)(ws + (size_t)100663296);
  float*    pSq   = (float*)(ws + (size_t)100663296 + 8388608);
  ushort_t* wqkvT = (ushort_t*)(ws + (size_t)134217728);
  ushort_t* woutT = (ushort_t*)(ws + (size_t)134217728 + 1572864);
  ushort_t* attn  = (ushort_t*)(ws + (size_t)134217728 + 2097152);

  prep_k<<<4096, 256, 0, stream>>>(w_qkv, w_out, wqkvT, woutT);
  rmsnorm_k<<<ROWS / 4, 256, 0, stream>>>(x, gamma, xn);
  gemm_bt<ushort_t><<<dim3(QKVN / 128, ROWS / 128), 256, 0, stream>>>(
      xn, wqkvT, qkv, ROWS, QKVN, NDIM);
  gram_k<<<dim3(8, 64), 256, 0, stream>>>(qkv, pG, pSq);
  softmax_k<<<64, 64, 0, stream>>>(pG, pSq, temp, attn);
  ot_k<<<dim3(32, 64), 256, 0, stream>>>(qkv, attn, OT);
  gemm_bt<float><<<dim3(NDIM / 128, ROWS / 128), 256, 0, stream>>>(
      OT, woutT, out, ROWS, NDIM, NDIM);
}

// Round 2
// 284.012 us; speedup vs baseline: 1.0873x; 1.0873x over previous
//
#include <hip/hip_runtime.h>
#include <stdint.h>

#define NDIM 512
#define HEADS 8
#define DHEAD 64
#define NSEQ 4096
#define BATCH 8
#define ROWS (BATCH * NSEQ)   // 32768
#define QKVN (3 * NDIM)       // 1536

typedef unsigned short ushort_t;
typedef __bf16 bf16x8 __attribute__((ext_vector_type(8)));
typedef float f32x4 __attribute__((ext_vector_type(4)));
typedef unsigned short u16x8 __attribute__((ext_vector_type(8)));
typedef unsigned short u16x4 __attribute__((ext_vector_type(4)));

__device__ __forceinline__ ushort_t f2bf(float f) {
  union { float f; uint32_t u; } v; v.f = f;
  uint32_t r = (v.u + 0x7FFFu + ((v.u >> 16) & 1u)) >> 16;
  return (ushort_t)r;
}
__device__ __forceinline__ float bf2f(ushort_t h) {
  union { uint32_t u; float f; } v; v.u = ((uint32_t)h) << 16;
  return v.f;
}

__device__ __forceinline__ void gload_lds16(const void* g, void* l) {
  __builtin_amdgcn_global_load_lds(
      (__attribute__((address_space(1))) void*)(g),
      (__attribute__((address_space(3))) void*)(l), 16, 0, 0);
}

// ---------- prep: coalesced LDS-tile transpose+cast of weights ----------
// w_qkv [512][1536] f32 -> wqkvT [1536][512] bf16 ; w_out [512][512] -> woutT [512][512]
__global__ __launch_bounds__(256) void prep_k(const float* __restrict__ w_qkv,
                                              const float* __restrict__ w_out,
                                              ushort_t* __restrict__ wqkvT,
                                              ushort_t* __restrict__ woutT) {
  __shared__ float tile[32][33];
  int id = blockIdx.x;
  const float* src;
  ushort_t* dst;
  int srcStride, ni, ki;
  if (id < 768) {               // 48 n-tiles x 16 k-tiles
    ni = id % 48; ki = id / 48; src = w_qkv; dst = wqkvT; srcStride = QKVN;
  } else {
    id -= 768;                  // 16 x 16
    ni = id % 16; ki = id / 16; src = w_out; dst = woutT; srcStride = NDIM;
  }
  int tr = threadIdx.x >> 3;          // 0..31
  int tc = (threadIdx.x & 7) * 4;     // 0..28
  float4 v = *(const float4*)(src + (size_t)(ki * 32 + tr) * srcStride + ni * 32 + tc);
  tile[tr][tc] = v.x; tile[tr][tc + 1] = v.y; tile[tr][tc + 2] = v.z; tile[tr][tc + 3] = v.w;
  __syncthreads();
  u16x4 o;
  o[0] = f2bf(tile[tc + 0][tr]);
  o[1] = f2bf(tile[tc + 1][tr]);
  o[2] = f2bf(tile[tc + 2][tr]);
  o[3] = f2bf(tile[tc + 3][tr]);
  *(u16x4*)(dst + (size_t)(ni * 32 + tr) * NDIM + ki * 32 + tc) = o;
}

// ---------- rmsnorm: xn = x/||x|| * sqrt(512) * gamma, bf16 out ----------
__global__ __launch_bounds__(256) void rmsnorm_k(const float* __restrict__ x,
                                                 const float* __restrict__ gamma,
                                                 ushort_t* __restrict__ xn) {
  int wave = threadIdx.x >> 6, lane = threadIdx.x & 63;
  size_t row = (size_t)blockIdx.x * 4 + wave;
  const float4* xr = (const float4*)(x + row * NDIM);
  float4 v0 = xr[lane * 2], v1 = xr[lane * 2 + 1];
  float s = v0.x*v0.x + v0.y*v0.y + v0.z*v0.z + v0.w*v0.w
          + v1.x*v1.x + v1.y*v1.y + v1.z*v1.z + v1.w*v1.w;
#pragma unroll
  for (int off = 32; off; off >>= 1) s += __shfl_xor(s, off, 64);
  float scale = 22.627416997969522f / fmaxf(sqrtf(s), 1e-12f);
  const float4* gr = (const float4*)gamma;
  float4 g0 = gr[lane * 2], g1 = gr[lane * 2 + 1];
  u16x8 o;
  o[0] = f2bf(v0.x * scale * g0.x);
  o[1] = f2bf(v0.y * scale * g0.y);
  o[2] = f2bf(v0.z * scale * g0.z);
  o[3] = f2bf(v0.w * scale * g0.w);
  o[4] = f2bf(v1.x * scale * g1.x);
  o[5] = f2bf(v1.y * scale * g1.y);
  o[6] = f2bf(v1.z * scale * g1.z);
  o[7] = f2bf(v1.w * scale * g1.w);
  *(u16x8*)(xn + row * NDIM + lane * 8) = o;
}

// ---------- 128x128 bf16 GEMM, C = A[M,K] @ BT[N,K]^T ----------
// LDS chunk stride 1088B (skew): alternate 8-row groups shift by 16 banks,
// turning the structural 16-way frag-read conflict into 8-way.
__device__ __forceinline__ void store_elem(float* C, size_t i, float v) { C[i] = v; }
__device__ __forceinline__ void store_elem(ushort_t* C, size_t i, float v) { C[i] = f2bf(v); }

#define CHUNK_US 544  // ushorts per 8-row chunk (1024B data + 64B skew pad)

template <typename T>
__global__ __launch_bounds__(256) void gemm_bt(const ushort_t* __restrict__ A,
                                               const ushort_t* __restrict__ BT,
                                               T* __restrict__ C,
                                               int M, int N, int K) {
  __shared__ ushort_t As[16 * CHUNK_US];
  __shared__ ushort_t Bs[16 * CHUNK_US];
  const int tid = threadIdx.x;
  const int lane = tid & 63;
  const int wave = tid >> 6;
  const int m0 = blockIdx.y * 128;
  const int n0 = blockIdx.x * 128;
  const int wm = (wave >> 1) * 64;
  const int wn = (wave & 1) * 64;
  const int srow = lane >> 3;
  const int scol = (lane & 7) * 16;  // bytes
  const int r = lane & 15, q = lane >> 4;

  f32x4 acc[4][4] = {};

  for (int k0 = 0; k0 < K; k0 += 64) {
    __syncthreads();
#pragma unroll
    for (int c = 0; c < 4; ++c) {
      int chunk = wave * 4 + c;
      int row = chunk * 8 + srow;
      gload_lds16((const char*)(A + (size_t)(m0 + row) * K + k0) + scol,
                  (char*)As + chunk * 1088);
      gload_lds16((const char*)(BT + (size_t)(n0 + row) * K + k0) + scol,
                  (char*)Bs + chunk * 1088);
    }
    __syncthreads();
#pragma unroll
    for (int kk = 0; kk < 64; kk += 32) {
      bf16x8 af[4], bfr[4];
#pragma unroll
      for (int i = 0; i < 4; ++i) {
        int row = wm + i * 16 + r;
        af[i] = *(const bf16x8*)(const void*)(As + (row >> 3) * CHUNK_US + (row & 7) * 64 + kk + q * 8);
      }
#pragma unroll
      for (int j = 0; j < 4; ++j) {
        int row = wn + j * 16 + r;
        bfr[j] = *(const bf16x8*)(const void*)(Bs + (row >> 3) * CHUNK_US + (row & 7) * 64 + kk + q * 8);
      }
#pragma unroll
      for (int i = 0; i < 4; ++i)
#pragma unroll
        for (int j = 0; j < 4; ++j)
          acc[i][j] = __builtin_amdgcn_mfma_f32_16x16x32_bf16(af[i], bfr[j], acc[i][j], 0, 0, 0);
    }
  }
#pragma unroll
  for (int i = 0; i < 4; ++i)
#pragma unroll
    for (int j = 0; j < 4; ++j) {
      int col = n0 + wn + j * 16 + r;
#pragma unroll
      for (int v = 0; v < 4; ++v) {
        int rw = m0 + wm + i * 16 + q * 4 + v;
        store_elem(C, (size_t)rw * N + col, acc[i][j][v]);
      }
    }
}

// ---------- gram partial: G[d,e] += sum_n Q[n,d]K[n,e], + col sumsq ----------
__global__ __launch_bounds__(256) void gram_k(const ushort_t* __restrict__ qkv,
                                              float* __restrict__ pG,
                                              float* __restrict__ pSq) {
  int chunk = blockIdx.x;  // 0..7  (n range chunk*512..+512)
  int bh = blockIdx.y;     // 0..63
  int b = bh >> 3, h = bh & 7;
  __shared__ ushort_t Qt[64 * 72];
  __shared__ ushort_t Kt[64 * 72];
  __shared__ float sq[128];
  int tid = threadIdx.x, lane = tid & 63, wave = tid >> 6;
  int nl = tid >> 2;          // 0..63 local n
  int dp = (tid & 3) * 16;    // d part
  int r = lane & 15, q = lane >> 4;
  float aq[16] = {}, ak[16] = {};
  f32x4 acc[4] = {};
  size_t base_row = ((size_t)b * NSEQ + (size_t)chunk * 512) * QKVN + (size_t)h * DHEAD;
  int swz_n = ((nl >> 3) & 7);

  for (int sc = 0; sc < 8; ++sc) {
    __syncthreads();
    size_t g = base_row + (size_t)(sc * 64 + nl) * QKVN;
    u16x8 qv0 = *(const u16x8*)(qkv + g + dp);
    u16x8 qv1 = *(const u16x8*)(qkv + g + dp + 8);
    u16x8 kv0 = *(const u16x8*)(qkv + g + NDIM + dp);
    u16x8 kv1 = *(const u16x8*)(qkv + g + NDIM + dp + 8);
#pragma unroll
    for (int i = 0; i < 8; ++i) {
      int d0 = dp + i, d1 = dp + 8 + i;
      int c0 = (nl & 7) | (((swz_n ^ (d0 >> 3)) & 7) << 3);
      int c1 = (nl & 7) | (((swz_n ^ (d1 >> 3)) & 7) << 3);
      float fq = bf2f(qv0[i]); aq[i] += fq * fq;      Qt[d0 * 72 + c0] = qv0[i];
      float fq2 = bf2f(qv1[i]); aq[8 + i] += fq2 * fq2; Qt[d1 * 72 + c1] = qv1[i];
      float fk = bf2f(kv0[i]); ak[i] += fk * fk;      Kt[d0 * 72 + c0] = kv0[i];
      float fk2 = bf2f(kv1[i]); ak[8 + i] += fk2 * fk2; Kt[d1 * 72 + c1] = kv1[i];
    }
    __syncthreads();
#pragma unroll
    for (int ks = 0; ks < 64; ks += 32) {
      int kb = (ks >> 3) + q;  // k block 0..7
      int m = wave * 16 + r;
      bf16x8 a = *(const bf16x8*)(const void*)(Qt + m * 72 + (((kb ^ (m >> 3)) & 7) << 3));
#pragma unroll
      for (int j = 0; j < 4; ++j) {
        int e = j * 16 + r;
        bf16x8 bb = *(const bf16x8*)(const void*)(Kt + e * 72 + (((kb ^ (e >> 3)) & 7) << 3));
        acc[j] = __builtin_amdgcn_mfma_f32_16x16x32_bf16(a, bb, acc[j], 0, 0, 0);
      }
    }
  }
  size_t gbase = ((size_t)bh * 8 + chunk) * 4096;
#pragma unroll
  for (int j = 0; j < 4; ++j)
#pragma unroll
    for (int v = 0; v < 4; ++v)
      pG[gbase + (size_t)(wave * 16 + q * 4 + v) * 64 + j * 16 + r] = acc[j][v];
  if (tid < 128) sq[tid] = 0.f;
  __syncthreads();
#pragma unroll
  for (int i = 0; i < 16; ++i) {
    atomicAdd(&sq[dp + i], aq[i]);
    atomicAdd(&sq[64 + dp + i], ak[i]);
  }
  __syncthreads();
  if (tid < 128) pSq[((size_t)bh * 8 + chunk) * 128 + tid] = sq[tid];
}

// ---------- finalize: norms + scale + softmax -> attn bf16 [bh][d][e] ----------
// 256 threads: thread t handles d = t>>2, e-range (t&3)*16..+15. float4 loads,
// 4-lane shfl reductions for row max/sum.
__global__ __launch_bounds__(256) void softmax_k(const float* __restrict__ pG,
                                                 const float* __restrict__ pSq,
                                                 const float* __restrict__ temp,
                                                 ushort_t* __restrict__ attn) {
  int bh = blockIdx.x;
  int h = bh & 7;
  int t = threadIdx.x;
  int d = t >> 2;
  int eg = (t & 3) * 16;
  __shared__ float kn[64];
  if (t < 64) {
    float sk = 0.f;
    for (int c = 0; c < 8; ++c) sk += pSq[((size_t)bh * 8 + c) * 128 + 64 + t];
    kn[t] = fmaxf(sqrtf(sk), 1e-12f);
  }
  float sq = 0.f;
  for (int c = 0; c < 8; ++c) sq += pSq[((size_t)bh * 8 + c) * 128 + d];
  float qn = fmaxf(sqrtf(sq), 1e-12f);
  __syncthreads();
  float scale = 8.0f * expf(temp[h]) / qn;
  float row[16];
#pragma unroll
  for (int k = 0; k < 16; ++k) row[k] = 0.f;
  for (int c = 0; c < 8; ++c) {
    const float4* src = (const float4*)(pG + ((size_t)bh * 8 + c) * 4096 + d * 64 + eg);
#pragma unroll
    for (int k4 = 0; k4 < 4; ++k4) {
      float4 v = src[k4];
      row[k4 * 4 + 0] += v.x; row[k4 * 4 + 1] += v.y;
      row[k4 * 4 + 2] += v.z; row[k4 * 4 + 3] += v.w;
    }
  }
#pragma unroll
  for (int k = 0; k < 16; ++k) row[k] = row[k] * scale / kn[eg + k];
  float mx = -1e30f;
#pragma unroll
  for (int k = 0; k < 16; ++k) mx = fmaxf(mx, row[k]);
  mx = fmaxf(mx, __shfl_xor(mx, 1, 64));
  mx = fmaxf(mx, __shfl_xor(mx, 2, 64));
  float s = 0.f;
#pragma unroll
  for (int k = 0; k < 16; ++k) { row[k] = expf(row[k] - mx); s += row[k]; }
  s += __shfl_xor(s, 1, 64);
  s += __shfl_xor(s, 2, 64);
  float inv = 1.0f / s;
  u16x8 o0, o1;
#pragma unroll
  for (int k = 0; k < 8; ++k) { o0[k] = f2bf(row[k] * inv); o1[k] = f2bf(row[8 + k] * inv); }
  ushort_t* dst = attn + (size_t)bh * 4096 + d * 64 + eg;
  *(u16x8*)dst = o0;
  *(u16x8*)(dst + 8) = o1;
}

// ---------- OT[n, h*64+d] = sum_e V[n,e]*attn[d,e] ----------
__global__ __launch_bounds__(256) void ot_k(const ushort_t* __restrict__ qkv,
                                            const ushort_t* __restrict__ attn,
                                            ushort_t* __restrict__ OT) {
  int nchunk = blockIdx.x;  // 0..31 (128 rows each)
  int bh = blockIdx.y;
  int b = bh >> 3, h = bh & 7;
  __shared__ ushort_t Vs[128 * 72];
  __shared__ ushort_t Am[64 * 72];
  int tid = threadIdx.x, lane = tid & 63, wave = tid >> 6;
  int r = lane & 15, q = lane >> 4;
  {  // stage attn [64][64] -> padded rows of 72
    int d = tid >> 2, p = (tid & 3) * 16;
    const u16x8* src = (const u16x8*)(attn + (size_t)bh * 4096 + d * 64 + p);
    *(u16x8*)(Am + d * 72 + p) = src[0];
    *(u16x8*)(Am + d * 72 + p + 8) = src[1];
  }
  {  // stage V [128][64] -> padded rows of 72 (half row / thread)
    int row = tid >> 1, p = (tid & 1) * 32;
    size_t vg = ((size_t)b * NSEQ + (size_t)nchunk * 128 + row) * QKVN + 2 * NDIM +
                (size_t)h * DHEAD + p;
    const u16x8* src = (const u16x8*)(qkv + vg);
    ushort_t* dst = Vs + row * 72 + p;
    *(u16x8*)(dst) = src[0];
    *(u16x8*)(dst + 8) = src[1];
    *(u16x8*)(dst + 16) = src[2];
    *(u16x8*)(dst + 24) = src[3];
  }
  __syncthreads();
  f32x4 acc[2][4] = {};
#pragma unroll
  for (int ks = 0; ks < 64; ks += 32) {
    bf16x8 av[2], bv[4];
#pragma unroll
    for (int i = 0; i < 2; ++i)
      av[i] = *(const bf16x8*)(const void*)(Vs + (wave * 32 + i * 16 + r) * 72 + ks + q * 8);
#pragma unroll
    for (int j = 0; j < 4; ++j)
      bv[j] = *(const bf16x8*)(const void*)(Am + (j * 16 + r) * 72 + ks + q * 8);
#pragma unroll
    for (int i = 0; i < 2; ++i)
#pragma unroll
      for (int j = 0; j < 4; ++j)
        acc[i][j] = __builtin_amdgcn_mfma_f32_16x16x32_bf16(av[i], bv[j], acc[i][j], 0, 0, 0);
  }
  size_t obase = ((size_t)b * NSEQ + (size_t)nchunk * 128) * NDIM + (size_t)h * DHEAD;
#pragma unroll
  for (int i = 0; i < 2; ++i)
#pragma unroll
    for (int j = 0; j < 4; ++j)
#pragma unroll
      for (int v = 0; v < 4; ++v)
        OT[obase + (size_t)(wave * 32 + i * 16 + q * 4 + v) * NDIM + j * 16 + r] =
            f2bf(acc[i][j][v]);
}

extern "C" void kernel_launch(void* const* d_in, const int* in_sizes, int n_in,
                              void* d_out, int out_size, void* d_ws, size_t ws_size,
                              hipStream_t stream) {
  (void)in_sizes; (void)n_in; (void)out_size; (void)ws_size;
  const float* x     = (const float*)d_in[0];
  const float* gamma = (const float*)d_in[1];
  const float* w_qkv = (const float*)d_in[2];
  const float* temp  = (const float*)d_in[3];
  const float* w_out = (const float*)d_in[4];
  float* out = (float*)d_out;
  char* ws = (char*)d_ws;

  // workspace layout (~130.5 MB):
  // [0, 96MB)        qkv bf16 [32768][1536]
  // [96MB, 128MB)    xn bf16 [32768][512]  -- after gemm1: pG (8MB) + pSq; then OT
  // [128MB, ...)     wqkvT (1.5MB), woutT (0.5MB), attn (0.5MB)
  ushort_t* qkv   = (ushort_t*)ws;
  ushort_t* xn    = (ushort_t*)(ws + (size_t)100663296);
  ushort_t* OT    = xn;
  float*    pG    = (float*)(ws + (size_t)100663296);
  float*    pSq   = (float*)(ws + (size_t)100663296 + 8388608);
  ushort_t* wqkvT = (ushort_t*)(ws + (size_t)134217728);
  ushort_t* woutT = (ushort_t*)(ws + (size_t)134217728 + 1572864);
  ushort_t* attn  = (ushort_t*)(ws + (size_t)134217728 + 2097152);

  prep_k<<<1024, 256, 0, stream>>>(w_qkv, w_out, wqkvT, woutT);
  rmsnorm_k<<<ROWS / 4, 256, 0, stream>>>(x, gamma, xn);
  gemm_bt<ushort_t><<<dim3(QKVN / 128, ROWS / 128), 256, 0, stream>>>(
      xn, wqkvT, qkv, ROWS, QKVN, NDIM);
  gram_k<<<dim3(8, 64), 256, 0, stream>>>(qkv, pG, pSq);
  softmax_k<<<64, 256, 0, stream>>>(pG, pSq, temp, attn);
  ot_k<<<dim3(32, 64), 256, 0, stream>>>(qkv, attn, OT);
  gemm_bt<float><<<dim3(NDIM / 128, ROWS / 128), 256, 0, stream>>>(
      OT, woutT, out, ROWS, NDIM, NDIM);
}

// Round 3
// 265.700 us; speedup vs baseline: 1.1622x; 1.0689x over previous
//
#include <hip/hip_runtime.h>
#include <stdint.h>

#define NDIM 512
#define HEADS 8
#define DHEAD 64
#define NSEQ 4096
#define BATCH 8
#define ROWS (BATCH * NSEQ)   // 32768
#define QKVN (3 * NDIM)       // 1536

typedef unsigned short ushort_t;
typedef __bf16 bf16x8 __attribute__((ext_vector_type(8)));
typedef float f32x4 __attribute__((ext_vector_type(4)));
typedef unsigned short u16x8 __attribute__((ext_vector_type(8)));
typedef unsigned short u16x4 __attribute__((ext_vector_type(4)));

__device__ __forceinline__ ushort_t f2bf(float f) {
  union { float f; uint32_t u; } v; v.f = f;
  uint32_t r = (v.u + 0x7FFFu + ((v.u >> 16) & 1u)) >> 16;
  return (ushort_t)r;
}
__device__ __forceinline__ float bf2f(ushort_t h) {
  union { uint32_t u; float f; } v; v.u = ((uint32_t)h) << 16;
  return v.f;
}

__device__ __forceinline__ void gload_lds16(const void* g, void* l) {
  __builtin_amdgcn_global_load_lds(
      (__attribute__((address_space(1))) void*)(g),
      (__attribute__((address_space(3))) void*)(l), 16, 0, 0);
}

// ---------- prep: coalesced LDS-tile transpose+cast of weights ----------
__global__ __launch_bounds__(256) void prep_k(const float* __restrict__ w_qkv,
                                              const float* __restrict__ w_out,
                                              ushort_t* __restrict__ wqkvT,
                                              ushort_t* __restrict__ woutT) {
  __shared__ float tile[32][33];
  int id = blockIdx.x;
  const float* src;
  ushort_t* dst;
  int srcStride, ni, ki;
  if (id < 768) {               // 48 n-tiles x 16 k-tiles
    ni = id % 48; ki = id / 48; src = w_qkv; dst = wqkvT; srcStride = QKVN;
  } else {
    id -= 768;                  // 16 x 16
    ni = id % 16; ki = id / 16; src = w_out; dst = woutT; srcStride = NDIM;
  }
  int tr = threadIdx.x >> 3;          // 0..31
  int tc = (threadIdx.x & 7) * 4;     // 0..28
  float4 v = *(const float4*)(src + (size_t)(ki * 32 + tr) * srcStride + ni * 32 + tc);
  tile[tr][tc] = v.x; tile[tr][tc + 1] = v.y; tile[tr][tc + 2] = v.z; tile[tr][tc + 3] = v.w;
  __syncthreads();
  u16x4 o;
  o[0] = f2bf(tile[tc + 0][tr]);
  o[1] = f2bf(tile[tc + 1][tr]);
  o[2] = f2bf(tile[tc + 2][tr]);
  o[3] = f2bf(tile[tc + 3][tr]);
  *(u16x4*)(dst + (size_t)(ni * 32 + tr) * NDIM + ki * 32 + tc) = o;
}

// ---------- rmsnorm: xn = x/||x|| * sqrt(512) * gamma, bf16 out ----------
__global__ __launch_bounds__(256) void rmsnorm_k(const float* __restrict__ x,
                                                 const float* __restrict__ gamma,
                                                 ushort_t* __restrict__ xn) {
  int wave = threadIdx.x >> 6, lane = threadIdx.x & 63;
  size_t row = (size_t)blockIdx.x * 4 + wave;
  const float4* xr = (const float4*)(x + row * NDIM);
  float4 v0 = xr[lane * 2], v1 = xr[lane * 2 + 1];
  float s = v0.x*v0.x + v0.y*v0.y + v0.z*v0.z + v0.w*v0.w
          + v1.x*v1.x + v1.y*v1.y + v1.z*v1.z + v1.w*v1.w;
#pragma unroll
  for (int off = 32; off; off >>= 1) s += __shfl_xor(s, off, 64);
  float scale = 22.627416997969522f / fmaxf(sqrtf(s), 1e-12f);
  const float4* gr = (const float4*)gamma;
  float4 g0 = gr[lane * 2], g1 = gr[lane * 2 + 1];
  u16x8 o;
  o[0] = f2bf(v0.x * scale * g0.x);
  o[1] = f2bf(v0.y * scale * g0.y);
  o[2] = f2bf(v0.z * scale * g0.z);
  o[3] = f2bf(v0.w * scale * g0.w);
  o[4] = f2bf(v1.x * scale * g1.x);
  o[5] = f2bf(v1.y * scale * g1.y);
  o[6] = f2bf(v1.z * scale * g1.z);
  o[7] = f2bf(v1.w * scale * g1.w);
  *(u16x8*)(xn + row * NDIM + lane * 8) = o;
}

// ---------- 128x128 bf16 GEMM, C = A[M,K] @ BT[N,K]^T ----------
// Staging XOR-swizzle: lane L fetches global k-block (L&7)^(L>>3) of its row,
// so LDS slot p of row rc holds block p^rc. Fragment reads address
// (kb ^ (row&7))*16B -> 8 lanes/chunk hit 8 distinct 16B slots = 32 banks,
// 16 lanes = 2/bank = conflict-free (m136). 1-D grid, XCD-stripe mapping:
// xcd = flat&7 owns contiguous M-stripe, N fastest -> A tiles stay in that
// XCD's L2 (working set ~3MB < 4MB).
__device__ __forceinline__ void store_elem(float* C, size_t i, float v) { C[i] = v; }
__device__ __forceinline__ void store_elem(ushort_t* C, size_t i, float v) { C[i] = f2bf(v); }

template <typename T, int NT>
__global__ __launch_bounds__(256) void gemm_bt(const ushort_t* __restrict__ A,
                                               const ushort_t* __restrict__ BT,
                                               T* __restrict__ C,
                                               int M, int N, int K) {
  __shared__ ushort_t As[16 * 512];
  __shared__ ushort_t Bs[16 * 512];
  const int tid = threadIdx.x;
  const int lane = tid & 63;
  const int wave = tid >> 6;

  const int flat = blockIdx.x;
  const int xcd = flat & 7;
  const int idx = flat >> 3;
  const int local_m = idx / NT;
  const int n_t = idx - local_m * NT;
  const int mt_per_xcd = (int)(gridDim.x / NT) >> 3;
  const int m0 = (xcd * mt_per_xcd + local_m) * 128;
  const int n0 = n_t * 128;

  const int wm = (wave >> 1) * 64;
  const int wn = (wave & 1) * 64;
  const int srow = lane >> 3;
  const int scol = ((lane & 7) ^ srow) * 16;  // bytes; XOR-swizzled source
  const int r = lane & 15, q = lane >> 4;

  f32x4 acc[4][4] = {};

  for (int k0 = 0; k0 < K; k0 += 64) {
    __syncthreads();
#pragma unroll
    for (int c = 0; c < 4; ++c) {
      int chunk = wave * 4 + c;
      int row = chunk * 8 + srow;
      gload_lds16((const char*)(A + (size_t)(m0 + row) * K + k0) + scol,
                  (char*)As + chunk * 1024);
      gload_lds16((const char*)(BT + (size_t)(n0 + row) * K + k0) + scol,
                  (char*)Bs + chunk * 1024);
    }
    __syncthreads();
#pragma unroll
    for (int kk = 0; kk < 64; kk += 32) {
      const int kb = (kk >> 3) + q;  // global 16B k-block 0..7
      bf16x8 af[4], bfr[4];
#pragma unroll
      for (int i = 0; i < 4; ++i) {
        int row = wm + i * 16 + r;
        af[i] = *(const bf16x8*)(const void*)(As + row * 64 + ((kb ^ (row & 7)) << 3));
      }
#pragma unroll
      for (int j = 0; j < 4; ++j) {
        int row = wn + j * 16 + r;
        bfr[j] = *(const bf16x8*)(const void*)(Bs + row * 64 + ((kb ^ (row & 7)) << 3));
      }
#pragma unroll
      for (int i = 0; i < 4; ++i)
#pragma unroll
        for (int j = 0; j < 4; ++j)
          acc[i][j] = __builtin_amdgcn_mfma_f32_16x16x32_bf16(af[i], bfr[j], acc[i][j], 0, 0, 0);
    }
  }
#pragma unroll
  for (int i = 0; i < 4; ++i)
#pragma unroll
    for (int j = 0; j < 4; ++j) {
      int col = n0 + wn + j * 16 + r;
#pragma unroll
      for (int v = 0; v < 4; ++v) {
        int rw = m0 + wm + i * 16 + q * 4 + v;
        store_elem(C, (size_t)rw * N + col, acc[i][j][v]);
      }
    }
}

// ---------- gram partial: G[d,e] += sum_n Q[n,d]K[n,e], + col sumsq ----------
__global__ __launch_bounds__(256) void gram_k(const ushort_t* __restrict__ qkv,
                                              float* __restrict__ pG,
                                              float* __restrict__ pSq) {
  int chunk = blockIdx.x;  // 0..7  (n range chunk*512..+512)
  int bh = blockIdx.y;     // 0..63
  int b = bh >> 3, h = bh & 7;
  __shared__ ushort_t Qt[64 * 72];
  __shared__ ushort_t Kt[64 * 72];
  __shared__ float sq[128];
  int tid = threadIdx.x, lane = tid & 63, wave = tid >> 6;
  int nl = tid >> 2;          // 0..63 local n
  int dp = (tid & 3) * 16;    // d part
  int r = lane & 15, q = lane >> 4;
  float aq[16] = {}, ak[16] = {};
  f32x4 acc[4] = {};
  size_t base_row = ((size_t)b * NSEQ + (size_t)chunk * 512) * QKVN + (size_t)h * DHEAD;
  int swz_n = ((nl >> 3) & 7);

  for (int sc = 0; sc < 8; ++sc) {
    __syncthreads();
    size_t g = base_row + (size_t)(sc * 64 + nl) * QKVN;
    u16x8 qv0 = *(const u16x8*)(qkv + g + dp);
    u16x8 qv1 = *(const u16x8*)(qkv + g + dp + 8);
    u16x8 kv0 = *(const u16x8*)(qkv + g + NDIM + dp);
    u16x8 kv1 = *(const u16x8*)(qkv + g + NDIM + dp + 8);
#pragma unroll
    for (int i = 0; i < 8; ++i) {
      int d0 = dp + i, d1 = dp + 8 + i;
      int c0 = (nl & 7) | (((swz_n ^ (d0 >> 3)) & 7) << 3);
      int c1 = (nl & 7) | (((swz_n ^ (d1 >> 3)) & 7) << 3);
      float fq = bf2f(qv0[i]); aq[i] += fq * fq;      Qt[d0 * 72 + c0] = qv0[i];
      float fq2 = bf2f(qv1[i]); aq[8 + i] += fq2 * fq2; Qt[d1 * 72 + c1] = qv1[i];
      float fk = bf2f(kv0[i]); ak[i] += fk * fk;      Kt[d0 * 72 + c0] = kv0[i];
      float fk2 = bf2f(kv1[i]); ak[8 + i] += fk2 * fk2; Kt[d1 * 72 + c1] = kv1[i];
    }
    __syncthreads();
#pragma unroll
    for (int ks = 0; ks < 64; ks += 32) {
      int kb = (ks >> 3) + q;  // k block 0..7
      int m = wave * 16 + r;
      bf16x8 a = *(const bf16x8*)(const void*)(Qt + m * 72 + (((kb ^ (m >> 3)) & 7) << 3));
#pragma unroll
      for (int j = 0; j < 4; ++j) {
        int e = j * 16 + r;
        bf16x8 bb = *(const bf16x8*)(const void*)(Kt + e * 72 + (((kb ^ (e >> 3)) & 7) << 3));
        acc[j] = __builtin_amdgcn_mfma_f32_16x16x32_bf16(a, bb, acc[j], 0, 0, 0);
      }
    }
  }
  size_t gbase = ((size_t)bh * 8 + chunk) * 4096;
#pragma unroll
  for (int j = 0; j < 4; ++j)
#pragma unroll
    for (int v = 0; v < 4; ++v)
      pG[gbase + (size_t)(wave * 16 + q * 4 + v) * 64 + j * 16 + r] = acc[j][v];
  if (tid < 128) sq[tid] = 0.f;
  __syncthreads();
#pragma unroll
  for (int i = 0; i < 16; ++i) {
    atomicAdd(&sq[dp + i], aq[i]);
    atomicAdd(&sq[64 + dp + i], ak[i]);
  }
  __syncthreads();
  if (tid < 128) pSq[((size_t)bh * 8 + chunk) * 128 + tid] = sq[tid];
}

// ---------- finalize: norms + scale + softmax -> attn bf16 [bh][d][e] ----------
__global__ __launch_bounds__(256) void softmax_k(const float* __restrict__ pG,
                                                 const float* __restrict__ pSq,
                                                 const float* __restrict__ temp,
                                                 ushort_t* __restrict__ attn) {
  int bh = blockIdx.x;
  int h = bh & 7;
  int t = threadIdx.x;
  int d = t >> 2;
  int eg = (t & 3) * 16;
  __shared__ float kn[64];
  if (t < 64) {
    float sk = 0.f;
    for (int c = 0; c < 8; ++c) sk += pSq[((size_t)bh * 8 + c) * 128 + 64 + t];
    kn[t] = fmaxf(sqrtf(sk), 1e-12f);
  }
  float sq = 0.f;
  for (int c = 0; c < 8; ++c) sq += pSq[((size_t)bh * 8 + c) * 128 + d];
  float qn = fmaxf(sqrtf(sq), 1e-12f);
  __syncthreads();
  float scale = 8.0f * expf(temp[h]) / qn;
  float row[16];
#pragma unroll
  for (int k = 0; k < 16; ++k) row[k] = 0.f;
  for (int c = 0; c < 8; ++c) {
    const float4* src = (const float4*)(pG + ((size_t)bh * 8 + c) * 4096 + d * 64 + eg);
#pragma unroll
    for (int k4 = 0; k4 < 4; ++k4) {
      float4 v = src[k4];
      row[k4 * 4 + 0] += v.x; row[k4 * 4 + 1] += v.y;
      row[k4 * 4 + 2] += v.z; row[k4 * 4 + 3] += v.w;
    }
  }
#pragma unroll
  for (int k = 0; k < 16; ++k) row[k] = row[k] * scale / kn[eg + k];
  float mx = -1e30f;
#pragma unroll
  for (int k = 0; k < 16; ++k) mx = fmaxf(mx, row[k]);
  mx = fmaxf(mx, __shfl_xor(mx, 1, 64));
  mx = fmaxf(mx, __shfl_xor(mx, 2, 64));
  float s = 0.f;
#pragma unroll
  for (int k = 0; k < 16; ++k) { row[k] = expf(row[k] - mx); s += row[k]; }
  s += __shfl_xor(s, 1, 64);
  s += __shfl_xor(s, 2, 64);
  float inv = 1.0f / s;
  u16x8 o0, o1;
#pragma unroll
  for (int k = 0; k < 8; ++k) { o0[k] = f2bf(row[k] * inv); o1[k] = f2bf(row[8 + k] * inv); }
  ushort_t* dst = attn + (size_t)bh * 4096 + d * 64 + eg;
  *(u16x8*)dst = o0;
  *(u16x8*)(dst + 8) = o1;
}

// ---------- OT[n, h*64+d] = sum_e V[n,e]*attn[d,e] ----------
__global__ __launch_bounds__(256) void ot_k(const ushort_t* __restrict__ qkv,
                                            const ushort_t* __restrict__ attn,
                                            ushort_t* __restrict__ OT) {
  int nchunk = blockIdx.x;  // 0..31 (128 rows each)
  int bh = blockIdx.y;
  int b = bh >> 3, h = bh & 7;
  __shared__ ushort_t Vs[128 * 72];
  __shared__ ushort_t Am[64 * 72];
  int tid = threadIdx.x, lane = tid & 63, wave = tid >> 6;
  int r = lane & 15, q = lane >> 4;
  {  // stage attn [64][64] -> padded rows of 72
    int d = tid >> 2, p = (tid & 3) * 16;
    const u16x8* src = (const u16x8*)(attn + (size_t)bh * 4096 + d * 64 + p);
    *(u16x8*)(Am + d * 72 + p) = src[0];
    *(u16x8*)(Am + d * 72 + p + 8) = src[1];
  }
  {  // stage V [128][64] -> padded rows of 72 (half row / thread)
    int row = tid >> 1, p = (tid & 1) * 32;
    size_t vg = ((size_t)b * NSEQ + (size_t)nchunk * 128 + row) * QKVN + 2 * NDIM +
                (size_t)h * DHEAD + p;
    const u16x8* src = (const u16x8*)(qkv + vg);
    ushort_t* dst = Vs + row * 72 + p;
    *(u16x8*)(dst) = src[0];
    *(u16x8*)(dst + 8) = src[1];
    *(u16x8*)(dst + 16) = src[2];
    *(u16x8*)(dst + 24) = src[3];
  }
  __syncthreads();
  f32x4 acc[2][4] = {};
#pragma unroll
  for (int ks = 0; ks < 64; ks += 32) {
    bf16x8 av[2], bv[4];
#pragma unroll
    for (int i = 0; i < 2; ++i)
      av[i] = *(const bf16x8*)(const void*)(Vs + (wave * 32 + i * 16 + r) * 72 + ks + q * 8);
#pragma unroll
    for (int j = 0; j < 4; ++j)
      bv[j] = *(const bf16x8*)(const void*)(Am + (j * 16 + r) * 72 + ks + q * 8);
#pragma unroll
    for (int i = 0; i < 2; ++i)
#pragma unroll
      for (int j = 0; j < 4; ++j)
        acc[i][j] = __builtin_amdgcn_mfma_f32_16x16x32_bf16(av[i], bv[j], acc[i][j], 0, 0, 0);
  }
  size_t obase = ((size_t)b * NSEQ + (size_t)nchunk * 128) * NDIM + (size_t)h * DHEAD;
#pragma unroll
  for (int i = 0; i < 2; ++i)
#pragma unroll
    for (int j = 0; j < 4; ++j)
#pragma unroll
      for (int v = 0; v < 4; ++v)
        OT[obase + (size_t)(wave * 32 + i * 16 + q * 4 + v) * NDIM + j * 16 + r] =
            f2bf(acc[i][j][v]);
}

extern "C" void kernel_launch(void* const* d_in, const int* in_sizes, int n_in,
                              void* d_out, int out_size, void* d_ws, size_t ws_size,
                              hipStream_t stream) {
  (void)in_sizes; (void)n_in; (void)out_size; (void)ws_size;
  const float* x     = (const float*)d_in[0];
  const float* gamma = (const float*)d_in[1];
  const float* w_qkv = (const float*)d_in[2];
  const float* temp  = (const float*)d_in[3];
  const float* w_out = (const float*)d_in[4];
  float* out = (float*)d_out;
  char* ws = (char*)d_ws;

  ushort_t* qkv   = (ushort_t*)ws;
  ushort_t* xn    = (ushort_t*)(ws + (size_t)100663296);
  ushort_t* OT    = xn;
  float*    pG    = (float*)(ws + (size_t)100663296);
  float*    pSq   = (float*)(ws + (size_t)100663296 + 8388608);
  ushort_t* wqkvT = (ushort_t*)(ws + (size_t)134217728);
  ushort_t* woutT = (ushort_t*)(ws + (size_t)134217728 + 1572864);
  ushort_t* attn  = (ushort_t*)(ws + (size_t)134217728 + 2097152);

  prep_k<<<1024, 256, 0, stream>>>(w_qkv, w_out, wqkvT, woutT);
  rmsnorm_k<<<ROWS / 4, 256, 0, stream>>>(x, gamma, xn);
  gemm_bt<ushort_t, 12><<<(QKVN / 128) * (ROWS / 128), 256, 0, stream>>>(
      xn, wqkvT, qkv, ROWS, QKVN, NDIM);
  gram_k<<<dim3(8, 64), 256, 0, stream>>>(qkv, pG, pSq);
  softmax_k<<<64, 256, 0, stream>>>(pG, pSq, temp, attn);
  ot_k<<<dim3(32, 64), 256, 0, stream>>>(qkv, attn, OT);
  gemm_bt<float, 4><<<(NDIM / 128) * (ROWS / 128), 256, 0, stream>>>(
      OT, woutT, out, ROWS, NDIM, NDIM);
}

// Round 4
// 260.811 us; speedup vs baseline: 1.1840x; 1.0187x over previous
//
#include <hip/hip_runtime.h>
#include <stdint.h>

#define NDIM 512
#define HEADS 8
#define DHEAD 64
#define NSEQ 4096
#define BATCH 8
#define ROWS (BATCH * NSEQ)   // 32768
#define QKVN (3 * NDIM)       // 1536

typedef unsigned short ushort_t;
typedef __bf16 bf16x8 __attribute__((ext_vector_type(8)));
typedef float f32x4 __attribute__((ext_vector_type(4)));
typedef unsigned short u16x8 __attribute__((ext_vector_type(8)));
typedef unsigned short u16x4 __attribute__((ext_vector_type(4)));

__device__ __forceinline__ ushort_t f2bf(float f) {
  union { float f; uint32_t u; } v; v.f = f;
  uint32_t r = (v.u + 0x7FFFu + ((v.u >> 16) & 1u)) >> 16;
  return (ushort_t)r;
}
__device__ __forceinline__ float bf2f(ushort_t h) {
  union { uint32_t u; float f; } v; v.u = ((uint32_t)h) << 16;
  return v.f;
}

__device__ __forceinline__ void gload_lds16(const void* g, void* l) {
  __builtin_amdgcn_global_load_lds(
      (__attribute__((address_space(1))) void*)(g),
      (__attribute__((address_space(3))) void*)(l), 16, 0, 0);
}

// ---------- prep: coalesced LDS-tile transpose+cast of weights ----------
__global__ __launch_bounds__(256) void prep_k(const float* __restrict__ w_qkv,
                                              const float* __restrict__ w_out,
                                              ushort_t* __restrict__ wqkvT,
                                              ushort_t* __restrict__ woutT) {
  __shared__ float tile[32][33];
  int id = blockIdx.x;
  const float* src;
  ushort_t* dst;
  int srcStride, ni, ki;
  if (id < 768) {               // 48 n-tiles x 16 k-tiles
    ni = id % 48; ki = id / 48; src = w_qkv; dst = wqkvT; srcStride = QKVN;
  } else {
    id -= 768;                  // 16 x 16
    ni = id % 16; ki = id / 16; src = w_out; dst = woutT; srcStride = NDIM;
  }
  int tr = threadIdx.x >> 3;          // 0..31
  int tc = (threadIdx.x & 7) * 4;     // 0..28
  float4 v = *(const float4*)(src + (size_t)(ki * 32 + tr) * srcStride + ni * 32 + tc);
  tile[tr][tc] = v.x; tile[tr][tc + 1] = v.y; tile[tr][tc + 2] = v.z; tile[tr][tc + 3] = v.w;
  __syncthreads();
  u16x4 o;
  o[0] = f2bf(tile[tc + 0][tr]);
  o[1] = f2bf(tile[tc + 1][tr]);
  o[2] = f2bf(tile[tc + 2][tr]);
  o[3] = f2bf(tile[tc + 3][tr]);
  *(u16x4*)(dst + (size_t)(ni * 32 + tr) * NDIM + ki * 32 + tc) = o;
}

// ---------- rmsnorm ----------
__global__ __launch_bounds__(256) void rmsnorm_k(const float* __restrict__ x,
                                                 const float* __restrict__ gamma,
                                                 ushort_t* __restrict__ xn) {
  int wave = threadIdx.x >> 6, lane = threadIdx.x & 63;
  size_t row = (size_t)blockIdx.x * 4 + wave;
  const float4* xr = (const float4*)(x + row * NDIM);
  float4 v0 = xr[lane * 2], v1 = xr[lane * 2 + 1];
  float s = v0.x*v0.x + v0.y*v0.y + v0.z*v0.z + v0.w*v0.w
          + v1.x*v1.x + v1.y*v1.y + v1.z*v1.z + v1.w*v1.w;
#pragma unroll
  for (int off = 32; off; off >>= 1) s += __shfl_xor(s, off, 64);
  float scale = 22.627416997969522f / fmaxf(sqrtf(s), 1e-12f);
  const float4* gr = (const float4*)gamma;
  float4 g0 = gr[lane * 2], g1 = gr[lane * 2 + 1];
  u16x8 o;
  o[0] = f2bf(v0.x * scale * g0.x);
  o[1] = f2bf(v0.y * scale * g0.y);
  o[2] = f2bf(v0.z * scale * g0.z);
  o[3] = f2bf(v0.w * scale * g0.w);
  o[4] = f2bf(v1.x * scale * g1.x);
  o[5] = f2bf(v1.y * scale * g1.y);
  o[6] = f2bf(v1.z * scale * g1.z);
  o[7] = f2bf(v1.w * scale * g1.w);
  *(u16x8*)(xn + row * NDIM + lane * 8) = o;
}

// ---------- QKV GEMM: qkv = xn[32768,512] @ wqkvT[1536,512]^T, bf16 out ----------
// XOR-swizzle staging (conflict-free frag reads), XCD M-stripes, LDS-bounce epilogue.
__global__ __launch_bounds__(256) void gemm_qkv(const ushort_t* __restrict__ A,
                                                const ushort_t* __restrict__ BT,
                                                ushort_t* __restrict__ C) {
  __shared__ ushort_t sm[17408];           // staging 2x8192; bounce [128][136]
  ushort_t* As = sm;
  ushort_t* Bs = sm + 8192;
  const int tid = threadIdx.x;
  const int lane = tid & 63;
  const int wave = tid >> 6;

  const int flat = blockIdx.x;             // 3072 blocks, NT=12
  const int xcd = flat & 7;
  const int idx = flat >> 3;
  const int local_m = idx / 12;
  const int n_t = idx - local_m * 12;
  const int m0 = (xcd * 32 + local_m) * 128;
  const int n0 = n_t * 128;

  const int wm = (wave >> 1) * 64;
  const int wn = (wave & 1) * 64;
  const int srow = lane >> 3;
  const int scol = ((lane & 7) ^ srow) * 16;
  const int r = lane & 15, q = lane >> 4;

  f32x4 acc[4][4] = {};

  for (int k0 = 0; k0 < NDIM; k0 += 64) {
    __syncthreads();
#pragma unroll
    for (int c = 0; c < 4; ++c) {
      int chunk = wave * 4 + c;
      int row = chunk * 8 + srow;
      gload_lds16((const char*)(A + (size_t)(m0 + row) * NDIM + k0) + scol,
                  (char*)As + chunk * 1024);
      gload_lds16((const char*)(BT + (size_t)(n0 + row) * NDIM + k0) + scol,
                  (char*)Bs + chunk * 1024);
    }
    __syncthreads();
#pragma unroll
    for (int kk = 0; kk < 64; kk += 32) {
      const int kb = (kk >> 3) + q;
      bf16x8 af[4], bfr[4];
#pragma unroll
      for (int i = 0; i < 4; ++i) {
        int row = wm + i * 16 + r;
        af[i] = *(const bf16x8*)(const void*)(As + row * 64 + ((kb ^ (row & 7)) << 3));
      }
#pragma unroll
      for (int j = 0; j < 4; ++j) {
        int row = wn + j * 16 + r;
        bfr[j] = *(const bf16x8*)(const void*)(Bs + row * 64 + ((kb ^ (row & 7)) << 3));
      }
#pragma unroll
      for (int i = 0; i < 4; ++i)
#pragma unroll
        for (int j = 0; j < 4; ++j)
          acc[i][j] = __builtin_amdgcn_mfma_f32_16x16x32_bf16(af[i], bfr[j], acc[i][j], 0, 0, 0);
    }
  }
  // LDS-bounce epilogue: [128][136] bf16 (rows 272B, 16B-aligned)
  __syncthreads();
#pragma unroll
  for (int i = 0; i < 4; ++i)
#pragma unroll
    for (int j = 0; j < 4; ++j)
#pragma unroll
      for (int v = 0; v < 4; ++v)
        sm[(wm + i * 16 + q * 4 + v) * 136 + wn + j * 16 + r] = f2bf(acc[i][j][v]);
  __syncthreads();
#pragma unroll
  for (int i = 0; i < 8; ++i) {
    int row = (tid >> 4) + 16 * i;
    int colB = (tid & 15) * 16;
    u16x8 val = *(const u16x8*)((const char*)sm + row * 272 + colB);
    *(u16x8*)((char*)(C + (size_t)(m0 + row) * QKVN + n0) + colB) = val;
  }
}

// ---------- gram partial: G[d,e] += sum_n Q[n,d]K[n,e], + col sumsq ----------
__global__ __launch_bounds__(256) void gram_k(const ushort_t* __restrict__ qkv,
                                              float* __restrict__ pG,
                                              float* __restrict__ pSq) {
  int chunk = blockIdx.x;  // 0..7
  int bh = blockIdx.y;     // 0..63
  int b = bh >> 3, h = bh & 7;
  __shared__ ushort_t Qt[64 * 72];
  __shared__ ushort_t Kt[64 * 72];
  __shared__ float sq[128];
  int tid = threadIdx.x, lane = tid & 63, wave = tid >> 6;
  int nl = tid >> 2;
  int dp = (tid & 3) * 16;
  int r = lane & 15, q = lane >> 4;
  float aq[16] = {}, ak[16] = {};
  f32x4 acc[4] = {};
  size_t base_row = ((size_t)b * NSEQ + (size_t)chunk * 512) * QKVN + (size_t)h * DHEAD;
  int swz_n = ((nl >> 3) & 7);
  // hoisted swizzled columns (only 2 distinct values per thread)
  int c_lo = (nl & 7) | (((swz_n ^ (dp >> 3)) & 7) << 3);
  int c_hi = (nl & 7) | (((swz_n ^ ((dp >> 3) + 1)) & 7) << 3);
  ushort_t* qlo = Qt + dp * 72 + c_lo;
  ushort_t* qhi = Qt + (dp + 8) * 72 + c_hi;
  ushort_t* klo = Kt + dp * 72 + c_lo;
  ushort_t* khi = Kt + (dp + 8) * 72 + c_hi;

  for (int sc = 0; sc < 8; ++sc) {
    __syncthreads();
    size_t g = base_row + (size_t)(sc * 64 + nl) * QKVN;
    u16x8 qv0 = *(const u16x8*)(qkv + g + dp);
    u16x8 qv1 = *(const u16x8*)(qkv + g + dp + 8);
    u16x8 kv0 = *(const u16x8*)(qkv + g + NDIM + dp);
    u16x8 kv1 = *(const u16x8*)(qkv + g + NDIM + dp + 8);
#pragma unroll
    for (int i = 0; i < 8; ++i) {
      float fq = bf2f(qv0[i]); aq[i] += fq * fq;       qlo[i * 72] = qv0[i];
      float fq2 = bf2f(qv1[i]); aq[8 + i] += fq2 * fq2; qhi[i * 72] = qv1[i];
      float fk = bf2f(kv0[i]); ak[i] += fk * fk;       klo[i * 72] = kv0[i];
      float fk2 = bf2f(kv1[i]); ak[8 + i] += fk2 * fk2; khi[i * 72] = kv1[i];
    }
    __syncthreads();
#pragma unroll
    for (int ks = 0; ks < 64; ks += 32) {
      int kb = (ks >> 3) + q;
      int m = wave * 16 + r;
      bf16x8 a = *(const bf16x8*)(const void*)(Qt + m * 72 + (((kb ^ (m >> 3)) & 7) << 3));
#pragma unroll
      for (int j = 0; j < 4; ++j) {
        int e = j * 16 + r;
        bf16x8 bb = *(const bf16x8*)(const void*)(Kt + e * 72 + (((kb ^ (e >> 3)) & 7) << 3));
        acc[j] = __builtin_amdgcn_mfma_f32_16x16x32_bf16(a, bb, acc[j], 0, 0, 0);
      }
    }
  }
  size_t gbase = ((size_t)bh * 8 + chunk) * 4096;
#pragma unroll
  for (int j = 0; j < 4; ++j)
#pragma unroll
    for (int v = 0; v < 4; ++v)
      pG[gbase + (size_t)(wave * 16 + q * 4 + v) * 64 + j * 16 + r] = acc[j][v];
  if (tid < 128) sq[tid] = 0.f;
  __syncthreads();
#pragma unroll
  for (int i = 0; i < 16; ++i) {
    atomicAdd(&sq[dp + i], aq[i]);
    atomicAdd(&sq[64 + dp + i], ak[i]);
  }
  __syncthreads();
  if (tid < 128) pSq[((size_t)bh * 8 + chunk) * 128 + tid] = sq[tid];
}

// ---------- softmax -> attnT bf16 [bh][e][d] (transposed for w2t) ----------
__global__ __launch_bounds__(256) void softmax_k(const float* __restrict__ pG,
                                                 const float* __restrict__ pSq,
                                                 const float* __restrict__ temp,
                                                 ushort_t* __restrict__ attnT) {
  int bh = blockIdx.x;
  int h = bh & 7;
  int t = threadIdx.x;
  int d = t >> 2;
  int eg = (t & 3) * 16;
  __shared__ float kn[64];
  if (t < 64) {
    float sk = 0.f;
    for (int c = 0; c < 8; ++c) sk += pSq[((size_t)bh * 8 + c) * 128 + 64 + t];
    kn[t] = fmaxf(sqrtf(sk), 1e-12f);
  }
  float sq = 0.f;
  for (int c = 0; c < 8; ++c) sq += pSq[((size_t)bh * 8 + c) * 128 + d];
  float qn = fmaxf(sqrtf(sq), 1e-12f);
  __syncthreads();
  float scale = 8.0f * expf(temp[h]) / qn;
  float row[16];
#pragma unroll
  for (int k = 0; k < 16; ++k) row[k] = 0.f;
  for (int c = 0; c < 8; ++c) {
    const float4* src = (const float4*)(pG + ((size_t)bh * 8 + c) * 4096 + d * 64 + eg);
#pragma unroll
    for (int k4 = 0; k4 < 4; ++k4) {
      float4 v = src[k4];
      row[k4 * 4 + 0] += v.x; row[k4 * 4 + 1] += v.y;
      row[k4 * 4 + 2] += v.z; row[k4 * 4 + 3] += v.w;
    }
  }
#pragma unroll
  for (int k = 0; k < 16; ++k) row[k] = row[k] * scale / kn[eg + k];
  float mx = -1e30f;
#pragma unroll
  for (int k = 0; k < 16; ++k) mx = fmaxf(mx, row[k]);
  mx = fmaxf(mx, __shfl_xor(mx, 1, 64));
  mx = fmaxf(mx, __shfl_xor(mx, 2, 64));
  float s = 0.f;
#pragma unroll
  for (int k = 0; k < 16; ++k) { row[k] = expf(row[k] - mx); s += row[k]; }
  s += __shfl_xor(s, 1, 64);
  s += __shfl_xor(s, 2, 64);
  float inv = 1.0f / s;
  // store transposed: attnT[e][d]
#pragma unroll
  for (int k = 0; k < 16; ++k)
    attnT[(size_t)bh * 4096 + (eg + k) * 64 + d] = f2bf(row[k] * inv);
}

// ---------- W2T[b][c][h*64+e] = sum_d woutT[c][h*64+d] * attnT[bh][e][d] ----------
__global__ __launch_bounds__(256) void w2t_k(const ushort_t* __restrict__ woutT,
                                             const ushort_t* __restrict__ attnT,
                                             ushort_t* __restrict__ W2T) {
  int mq = blockIdx.x;      // 0..3 (128 rows of c each)
  int bh = blockIdx.y;
  int b = bh >> 3, h = bh & 7;
  int tid = threadIdx.x, lane = tid & 63, wave = tid >> 6;
  int r = lane & 15, q = lane >> 4;
  int mbase = mq * 128 + wave * 32;
  const ushort_t* At = attnT + (size_t)bh * 4096;
  f32x4 acc[2][4] = {};
#pragma unroll
  for (int kk = 0; kk < 64; kk += 32) {
    bf16x8 a[2], bb[4];
#pragma unroll
    for (int mf = 0; mf < 2; ++mf)
      a[mf] = *(const bf16x8*)(woutT + (size_t)(mbase + mf * 16 + r) * NDIM + h * 64 + kk + q * 8);
#pragma unroll
    for (int nf = 0; nf < 4; ++nf)
      bb[nf] = *(const bf16x8*)(At + (nf * 16 + r) * 64 + kk + q * 8);
#pragma unroll
    for (int mf = 0; mf < 2; ++mf)
#pragma unroll
      for (int nf = 0; nf < 4; ++nf)
        acc[mf][nf] = __builtin_amdgcn_mfma_f32_16x16x32_bf16(a[mf], bb[nf], acc[mf][nf], 0, 0, 0);
  }
#pragma unroll
  for (int mf = 0; mf < 2; ++mf)
#pragma unroll
    for (int nf = 0; nf < 4; ++nf)
#pragma unroll
      for (int v = 0; v < 4; ++v)
        W2T[(size_t)b * 262144 + (size_t)(mbase + mf * 16 + q * 4 + v) * NDIM +
            h * 64 + nf * 16 + r] = f2bf(acc[mf][nf][v]);
}

// ---------- final: out[b] = V[b] @ W2T[b]^T  (V read from qkv, f32 out) ----------
__global__ __launch_bounds__(256) void gemm_v(const ushort_t* __restrict__ qkv,
                                              const ushort_t* __restrict__ W2T,
                                              float* __restrict__ out) {
  __shared__ ushort_t sm[17408];           // staging 2x8192; bounce [64][132] f32
  ushort_t* As = sm;
  ushort_t* Bs = sm + 8192;
  float* Cb = (float*)sm;
  const int tid = threadIdx.x;
  const int lane = tid & 63;
  const int wave = tid >> 6;

  const int flat = blockIdx.x;   // 1024: xcd = b
  const int b = flat & 7;
  const int local = flat >> 3;   // 0..127
  const int mt = local >> 2, nt = local & 3;
  const int m0 = mt * 128, n0 = nt * 128;
  const size_t abase = (size_t)b * NSEQ;
  const ushort_t* BT = W2T + (size_t)b * 262144;

  const int wm = (wave >> 1) * 64;
  const int wn = (wave & 1) * 64;
  const int srow = lane >> 3;
  const int scol = ((lane & 7) ^ srow) * 16;
  const int r = lane & 15, q = lane >> 4;

  f32x4 acc[4][4] = {};

  for (int k0 = 0; k0 < NDIM; k0 += 64) {
    __syncthreads();
#pragma unroll
    for (int c = 0; c < 4; ++c) {
      int chunk = wave * 4 + c;
      int row = chunk * 8 + srow;
      gload_lds16((const char*)(qkv + (abase + m0 + row) * QKVN + 1024 + k0) + scol,
                  (char*)As + chunk * 1024);
      gload_lds16((const char*)(BT + (size_t)(n0 + row) * NDIM + k0) + scol,
                  (char*)Bs + chunk * 1024);
    }
    __syncthreads();
#pragma unroll
    for (int kk = 0; kk < 64; kk += 32) {
      const int kb = (kk >> 3) + q;
      bf16x8 af[4], bfr[4];
#pragma unroll
      for (int i = 0; i < 4; ++i) {
        int row = wm + i * 16 + r;
        af[i] = *(const bf16x8*)(const void*)(As + row * 64 + ((kb ^ (row & 7)) << 3));
      }
#pragma unroll
      for (int j = 0; j < 4; ++j) {
        int row = wn + j * 16 + r;
        bfr[j] = *(const bf16x8*)(const void*)(Bs + row * 64 + ((kb ^ (row & 7)) << 3));
      }
#pragma unroll
      for (int i = 0; i < 4; ++i)
#pragma unroll
        for (int j = 0; j < 4; ++j)
          acc[i][j] = __builtin_amdgcn_mfma_f32_16x16x32_bf16(af[i], bfr[j], acc[i][j], 0, 0, 0);
    }
  }
  // two-phase f32 LDS-bounce epilogue: [64][132] f32 per phase
#pragma unroll
  for (int p = 0; p < 2; ++p) {
    __syncthreads();
    if (wm == p * 64) {
#pragma unroll
      for (int i = 0; i < 4; ++i)
#pragma unroll
        for (int j = 0; j < 4; ++j)
#pragma unroll
          for (int v = 0; v < 4; ++v)
            Cb[(i * 16 + q * 4 + v) * 132 + wn + j * 16 + r] = acc[i][j][v];
    }
    __syncthreads();
#pragma unroll
    for (int i = 0; i < 8; ++i) {
      int row = (tid >> 3) + 32 * (i & 1);
      int col = (tid & 7) * 4 + (i >> 1) * 32;
      f32x4 val = *(const f32x4*)(Cb + row * 132 + col);
      *(f32x4*)(out + (abase + m0 + p * 64 + row) * NDIM + n0 + col) = val;
    }
  }
}

extern "C" void kernel_launch(void* const* d_in, const int* in_sizes, int n_in,
                              void* d_out, int out_size, void* d_ws, size_t ws_size,
                              hipStream_t stream) {
  (void)in_sizes; (void)n_in; (void)out_size; (void)ws_size;
  const float* x     = (const float*)d_in[0];
  const float* gamma = (const float*)d_in[1];
  const float* w_qkv = (const float*)d_in[2];
  const float* temp  = (const float*)d_in[3];
  const float* w_out = (const float*)d_in[4];
  float* out = (float*)d_out;
  char* ws = (char*)d_ws;

  // workspace layout (~136.8 MB peak, same as R3):
  // [0, 96MB)        qkv bf16 [32768][1536]
  // [96MB, 128MB)    xn bf16; after gemm1: pG (8MB) + pSq (0.25MB) + W2T (4MB @ +12MB)
  // [128MB, ...)     wqkvT (1.5MB), woutT (0.5MB), attnT (0.5MB)
  ushort_t* qkv   = (ushort_t*)ws;
  ushort_t* xn    = (ushort_t*)(ws + (size_t)100663296);
  float*    pG    = (float*)(ws + (size_t)100663296);
  float*    pSq   = (float*)(ws + (size_t)100663296 + 8388608);
  ushort_t* W2T   = (ushort_t*)(ws + (size_t)100663296 + 12582912);
  ushort_t* wqkvT = (ushort_t*)(ws + (size_t)134217728);
  ushort_t* woutT = (ushort_t*)(ws + (size_t)134217728 + 1572864);
  ushort_t* attnT = (ushort_t*)(ws + (size_t)134217728 + 2097152);

  prep_k<<<1024, 256, 0, stream>>>(w_qkv, w_out, wqkvT, woutT);
  rmsnorm_k<<<ROWS / 4, 256, 0, stream>>>(x, gamma, xn);
  gemm_qkv<<<(QKVN / 128) * (ROWS / 128), 256, 0, stream>>>(xn, wqkvT, qkv);
  gram_k<<<dim3(8, 64), 256, 0, stream>>>(qkv, pG, pSq);
  softmax_k<<<64, 256, 0, stream>>>(pG, pSq, temp, attnT);
  w2t_k<<<dim3(4, 64), 256, 0, stream>>>(woutT, attnT, W2T);
  gemm_v<<<(NDIM / 128) * (ROWS / 128), 256, 0, stream>>>(qkv, W2T, out);
}